// Round 14
// baseline (278.481 us; speedup 1.0000x reference)
//
#include <hip/hip_runtime.h>
#include <hip/hip_bf16.h>
#include <math.h>

#define BB 2
#define D 48
#define HH 64
#define WW 64
#define LL 4096      // HH*WW
#define NHEADS 4
#define HD 12
#define NBLK 4
#define CUP 768
#define H2 256
#define W2 256

#define NSPLIT 4
#define OPART_STRIDE 393216   // B*L*48 floats per split

typedef __attribute__((ext_vector_type(8))) short short8v;
typedef __attribute__((ext_vector_type(4))) float f32x4;
typedef unsigned long long u64;

__device__ __forceinline__ short f2bf(float f) {
    __hip_bfloat16 h = __float2bfloat16(f);
    union { __hip_bfloat16 b; short s; } u; u.b = h; return u.s;
}
__device__ __forceinline__ float bf2f(short s) {
    union { float f; unsigned u; } x;
    x.u = ((unsigned)(unsigned short)s) << 16;
    return x.f;
}
// raw 2^x (hardware approx, ~1 ulp; inputs are tiny softmax scores -> safe)
__device__ __forceinline__ float exp2_raw(float x) {
    float r; asm("v_exp_f32 %0, %1" : "=v"(r) : "v"(x)); return r;
}

// ---------------- generic 3x3 SAME conv, f32 (used for conv_first only) ----------------
__global__ void conv3x3_kernel(const float* __restrict__ in, const float* __restrict__ w,
                               const float* __restrict__ bias, float* __restrict__ out,
                               int Cin, int Cout) {
    int idx = blockIdx.x * blockDim.x + threadIdx.x;
    int total = BB * Cout * HH * WW;
    if (idx >= total) return;
    int x = idx % WW;
    int y = (idx / WW) % HH;
    int co = (idx / (WW * HH)) % Cout;
    int b = idx / (WW * HH * Cout);
    float s = bias[co];
    for (int ci = 0; ci < Cin; ci++) {
        const float* ip = in + ((size_t)(b * Cin + ci) * HH) * WW;
        const float* wp = w + (size_t)(co * Cin + ci) * 9;
        #pragma unroll
        for (int ky = 0; ky < 3; ky++) {
            int iy = y + ky - 1;
            if (iy < 0 || iy >= HH) continue;
            #pragma unroll
            for (int kx = 0; kx < 3; kx++) {
                int ix = x + kx - 1;
                if (ix < 0 || ix >= WW) continue;
                s += ip[iy * WW + ix] * wp[ky * 3 + kx];
            }
        }
    }
    out[idx] = s;
}

// ---- pack h (NCHW f32) -> bf16 channel-last with 1-px zero halo: [b][66][66][48] + 64 zero ----
__global__ __launch_bounds__(256) void pack_h_kernel(const float* __restrict__ h,
                                                     short* __restrict__ hbfp) {
    int idx = blockIdx.x * 256 + threadIdx.x;
    const int TOT = 2 * 66 * 66 * 48;    // 418176
    if (idx >= TOT + 64) return;
    if (idx >= TOT) { hbfp[idx] = 0; return; }
    int ci = idx % 48;
    int p = idx / 48;
    int xx = p % 66;
    int q = p / 66;
    int yy = q % 66;
    int b = q / 66;
    short v = 0;
    if (yy >= 1 && yy <= 64 && xx >= 1 && xx <= 64)
        v = f2bf(h[((size_t)(b * 48 + ci) << 12) + (yy - 1) * 64 + (xx - 1)]);
    hbfp[idx] = v;
}

// ---- pack conv_up weights into B-fragment order: Wp[n16][s][col][g][j], K=tap*48+ci pad 448 ----
__global__ __launch_bounds__(256) void pack_w_kernel(const float* __restrict__ w,
                                                     short* __restrict__ Wp) {
    int idx = blockIdx.x * 256 + threadIdx.x;
    if (idx >= 48 * 14 * 512) return;    // 344064
    int j = idx & 7;
    int g = (idx >> 3) & 3;
    int col = (idx >> 5) & 15;
    int s = (idx >> 9) % 14;
    int n16 = idx / (14 * 512);
    int k = 32 * s + 8 * g + j;
    short v = 0;
    if (k < 432) {
        int tap = k / 48, ci = k - tap * 48;
        int co = n16 * 16 + col;
        v = f2bf(w[((size_t)co * 48 + ci) * 9 + tap]);
    }
    Wp[idx] = v;
}

// ---- pack last-conv weights into B-fragment order: Wp2[s][col][g][j], cols 3..15 zero ----
__global__ __launch_bounds__(256) void pack_lw_kernel(const float* __restrict__ w,
                                                      short* __restrict__ Wp2) {
    int idx = blockIdx.x * 256 + threadIdx.x;
    if (idx >= 14 * 512) return;         // 7168
    int j = idx & 7;
    int g = (idx >> 3) & 3;
    int col = (idx >> 5) & 15;
    int s = idx >> 9;
    int k = 32 * s + 8 * g + j;
    short v = 0;
    if (k < 432 && col < 3) {
        int tap = k / 48, ci = k - tap * 48;
        v = f2bf(w[((size_t)col * 48 + ci) * 9 + tap]);
    }
    Wp2[idx] = v;
}

// ---- conv_up as bf16 MFMA GEMM, n-split (R13-proven): block (128 thr) owns one
//      16-px strip; wave w computes n-tiles [24w, 24w+24). Staging: shared LDS,
//      waves write/store DISJOINT 24-channel columns -> no race, NO sync. ----
#define CU_LOADB(P, n) { \
    _Pragma("unroll") \
    for (int s_ = 0; s_ < 14; s_++) \
        P[s_] = *(const short8v*)(Wb + (size_t)(n) * 7168 + s_ * 512); }

#define CU_COMP(P, n) { \
    f32x4 acc = {0.f, 0.f, 0.f, 0.f}; \
    _Pragma("unroll") \
    for (int s_ = 0; s_ < 14; s_++) \
        acc = __builtin_amdgcn_mfma_f32_16x16x32_bf16(av[s_], P[s_], acc, 0, 0, 0); \
    float bval = bias[(n) * 16 + col]; \
    _Pragma("unroll") \
    for (int j = 0; j < 4; j++) \
        Sw[sbase + j * 192 + (n)] = f2bf(acc[j] + bval); }

__global__ __launch_bounds__(128) void conv_up_mfma_kernel(const short* __restrict__ hbfp,
                                                           const short* __restrict__ Wp,
                                                           const float* __restrict__ bias,
                                                           short* __restrict__ U) {
    __shared__ short Sw[12288];          // 24 KB [dyq 4][pos 64][ch 48]; disjoint n cols/wave
    int tid = threadIdx.x;
    int wave = tid >> 6, lane = tid & 63;
    int mt = blockIdx.x;                 // 512 strips: b(2) | y(64) | xt(4)
    int b = mt >> 8;
    int rem = mt & 255;
    int y = rem >> 2;
    int xt = rem & 3;
    int col = lane & 15;
    int g = lane >> 4;
    int x = xt * 16 + col;               // A-row pixel x

    const short* zb = hbfp + 2 * 66 * 66 * 48;   // 64 zero shorts

    // A fragments in registers, loaded once per wave (same im2col addressing)
    short8v av[14];
    #pragma unroll
    for (int s = 0; s < 14; s++) {
        int gg = 4 * s + g;
        int tap = (gg * 171) >> 10;      // gg/6 for gg<60
        int cig = gg - tap * 6;
        int dy = (tap * 11) >> 5;        // tap/3 for tap<9(+)
        int dx = tap - dy * 3;
        const short* ap = hbfp + ((size_t)((b * 66 + y + dy) * 66 + (x + dx)) * 48 + cig * 8);
        ap = (gg < 54) ? ap : zb;
        av[s] = *(const short8v*)ap;
    }

    const short* Wb = Wp + col * 32 + g * 8;
    int dyq = col >> 2, dxq = col & 3;
    int sbase = dyq * 3072 + (16 * g + dxq) * 48;   // + j*192 + n
    int n0 = wave * 24;                  // this wave's n-half

    short8v Ba[14], Bb[14];
    CU_LOADB(Ba, n0);
    for (int n = n0; n < n0 + 24; n += 2) {
        CU_LOADB(Bb, n + 1);
        CU_COMP(Ba, n);
        if (n + 2 < n0 + 24) CU_LOADB(Ba, n + 2);
        CU_COMP(Bb, n + 1);
    }

    // wave-private store of its 24-channel half: 4 rows x 64 positions, 48-B runs
    short* Ub = U + (((size_t)(b * 256 + 4 * y) * 256) + xt * 64) * 48 + n0;
    for (int i = lane; i < 256; i += 64) {
        int row = i >> 6;                // 0..3
        int xx2 = i & 63;
        const short* src = Sw + row * 3072 + xx2 * 48 + n0;
        short* dst = Ub + ((size_t)row * 256 + xx2) * 48;
        *(short8v*)(dst)      = *(const short8v*)(src);
        *(short8v*)(dst + 8)  = *(const short8v*)(src + 8);
        *(short8v*)(dst + 16) = *(const short8v*)(src + 16);
    }
}

// ---- zero bf16 pad regions; plant bf16 1.0 in Vr's padded row dd==12 (sum-row trick) ----
__global__ void zero16_kernel(u64* __restrict__ p, int n) {
    int i = blockIdx.x * 256 + threadIdx.x;
    if (i >= n) return;
    u64 fill = 0ull;
    // short offset of this 8-short chunk, relative to Vr start (Q:1M + K:1M shorts before it)
    int rel = 8 * i - 2097152;
    if (rel >= 0 && rel < 524288 && (((rel >> 5) & 15) == 12))
        fill = 0x3F803F803F803F80ull;     // bf16 1.0 x4
    p[2 * i] = fill;
    p[2 * i + 1] = fill;
}

// ---- fused: LN1 (NCHW) -> ln1 rows + qkv matmul -> bf16 Q/K/Vr (16-tok tiles) ----
__global__ __launch_bounds__(256) void fused_ln1_qkv_kernel(
    const float* __restrict__ hsrc, const float* __restrict__ g1, const float* __restrict__ b1,
    const float* __restrict__ w, const float* __restrict__ bias,
    float* __restrict__ ln1, short* __restrict__ Qbf, short* __restrict__ Kbf,
    short* __restrict__ Vr) {
    __shared__ float hs[48 * 17];
    __shared__ float lnr[16 * 49];
    __shared__ float wl[48 * 144];
    int blk = blockIdx.x;
    int b = blk >> 8;
    int pos0 = (blk & 255) * 16;
    int tid = threadIdx.x;

    for (int i = tid; i < 48 * 144; i += 256) wl[i] = w[i];
    for (int i = tid; i < 48 * 16; i += 256) {
        int ch = i >> 4, p = i & 15;
        hs[ch * 17 + p] = hsrc[((size_t)b * 48 + ch) * 4096 + pos0 + p];
    }
    __syncthreads();

    int tok = tid >> 4, oct = tid & 15;
    int pos = pos0 + tok;
    float v[3];
    float s = 0.f, s2 = 0.f;
    #pragma unroll
    for (int j = 0; j < 3; j++) {
        float x = hs[(oct * 3 + j) * 17 + tok];
        v[j] = x; s += x; s2 += x * x;
    }
    #pragma unroll
    for (int msk = 1; msk < 16; msk <<= 1) {
        s += __shfl_xor(s, msk, 64);
        s2 += __shfl_xor(s2, msk, 64);
    }
    float mu = s * (1.f / 48.f);
    float var = s2 * (1.f / 48.f) - mu * mu;
    float rs = rsqrtf(var + 1e-5f);
    float* go = ln1 + ((size_t)b * 4096 + pos) * 48 + oct * 3;
    #pragma unroll
    for (int j = 0; j < 3; j++) {
        int c = oct * 3 + j;
        float y = (v[j] - mu) * rs * g1[c] + b1[c];
        lnr[tok * 49 + c] = y;
        go[j] = y;
    }
    __syncthreads();

    int c0 = oct * 9;
    float acc[9];
    #pragma unroll
    for (int j = 0; j < 9; j++) acc[j] = bias[c0 + j];
    #pragma unroll 4
    for (int k = 0; k < 48; k++) {
        float a = lnr[tok * 49 + k];
        const float* wr = wl + k * 144 + c0;
        #pragma unroll
        for (int j = 0; j < 9; j++) acc[j] += a * wr[j];
    }

    // 1/sqrt(12) * log2(e): softmax exp becomes a single raw v_exp_f32 (2^x)
    const float scale = 0.41647023f;
    int sstep = pos >> 5, r = pos & 31;
    int g2 = (r < 16) ? (r >> 2) : ((r - 16) >> 2);
    int j2 = (r < 16) ? (r & 3) : 4 + ((r - 16) & 3);
    #pragma unroll
    for (int j = 0; j < 9; j++) {
        int c = c0 + j;
        int which = (c >= 96) ? 2 : (c >= 48 ? 1 : 0);
        int rem = c - which * 48;
        int hh = rem / 12;
        int dd = rem - hh * 12;
        int bh = b * 4 + hh;
        if (which == 0)
            Qbf[((size_t)bh * 4096 + pos) * 32 + dd] = f2bf(acc[j] * scale);
        else if (which == 1)
            Kbf[((size_t)bh * 4096 + pos) * 32 + dd] = f2bf(acc[j]);
        else
            Vr[((size_t)bh * 128 + sstep) * 512 + dd * 32 + g2 * 8 + j2] = f2bf(acc[j]);
    }
}

// ---- fused: split-combine + proj + resid + LN2 + fc1 + GELU + fc2 + resid + h-accum ----
__global__ __launch_bounds__(256) void fused_mlp_kernel(
    const float* __restrict__ opart, const float* __restrict__ ssump,
    const float* __restrict__ pwg, const float* __restrict__ pb,
    const float* __restrict__ ln1, const float* __restrict__ g2v, const float* __restrict__ b2v,
    const float* __restrict__ f1w, const float* __restrict__ f1b,
    const float* __restrict__ f2w, const float* __restrict__ f2b,
    float* __restrict__ hbuf) {
    __shared__ float sm[14640];
    float* wp  = sm;            // 2304  (48x48 proj)
    float* w1  = sm + 2304;     // 4608  (48x96 fc1)
    float* w2  = sm + 6912;     // 4608  (96x48 fc2)
    float* arf = sm + 11520;    // 784   (16x49) attn rows, reused as fc2-out
    float* lnr = sm + 12304;    // 784   (16x49) ln2 rows
    float* m1v = sm + 13088;    // 1552  (16x97) gelu(fc1)

    int blk = blockIdx.x;
    int b = blk >> 8;
    int pos0 = (blk & 255) * 16;
    int tid = threadIdx.x;

    for (int i = tid; i < 2304; i += 256) wp[i] = pwg[i];
    for (int i = tid; i < 4608; i += 256) w1[i] = f1w[i];
    for (int i = tid; i < 4608; i += 256) w2[i] = f2w[i];
    // combine split partials -> normalized attention rows (per-thread, no extra sync deps)
    for (int i = tid; i < 768; i += 256) {
        int t = i / 48, c = i - (i / 48) * 48;
        int hh = c / 12;
        size_t base = ((size_t)b * 4096 + pos0) * 48 + i;
        float stot = 0.f, s = 0.f;
        #pragma unroll
        for (int sp = 0; sp < NSPLIT; sp++) {
            stot += ssump[((size_t)sp * 8 + b * 4 + hh) * 4096 + pos0 + t];
            s += opart[base + (size_t)sp * OPART_STRIDE];
        }
        arf[t * 49 + c] = s / stot;
    }
    __syncthreads();

    int tok = tid >> 4, oct = tid & 15;
    size_t gtok = (size_t)b * 4096 + pos0 + tok;
    int c0 = oct * 3;
    float acc[3];
    #pragma unroll
    for (int j = 0; j < 3; j++) acc[j] = pb[c0 + j];
    #pragma unroll 4
    for (int k = 0; k < 48; k++) {
        float a = arf[tok * 49 + k];
        const float* wr = wp + k * 48 + c0;
        #pragma unroll
        for (int j = 0; j < 3; j++) acc[j] += a * wr[j];
    }
    const float* rp = ln1 + gtok * 48 + c0;
    float x[3]; float s = 0.f, s2 = 0.f;
    #pragma unroll
    for (int j = 0; j < 3; j++) {
        float t = acc[j] + rp[j];
        x[j] = t; s += t; s2 += t * t;
    }
    #pragma unroll
    for (int msk = 1; msk < 16; msk <<= 1) {
        s += __shfl_xor(s, msk, 64);
        s2 += __shfl_xor(s2, msk, 64);
    }
    float mu = s * (1.f / 48.f), var = s2 * (1.f / 48.f) - mu * mu;
    float rs = rsqrtf(var + 1e-5f);
    #pragma unroll
    for (int j = 0; j < 3; j++) {
        int c = c0 + j;
        lnr[tok * 49 + c] = (x[j] - mu) * rs * g2v[c] + b2v[c];
    }
    __syncthreads();

    // fc1 + GELU -> m1v (LDS only)
    int d0 = oct * 6;
    float a2[6];
    #pragma unroll
    for (int j = 0; j < 6; j++) a2[j] = f1b[d0 + j];
    #pragma unroll 4
    for (int k = 0; k < 48; k++) {
        float a = lnr[tok * 49 + k];
        const float* wr = w1 + k * 96 + d0;
        #pragma unroll
        for (int j = 0; j < 6; j++) a2[j] += a * wr[j];
    }
    #pragma unroll
    for (int j = 0; j < 6; j++) {
        float g = a2[j];
        m1v[tok * 97 + d0 + j] = 0.5f * g * (1.f + erff(g * 0.70710678118654752f));
    }
    __syncthreads();

    // fc2 + ln2-residual -> arf (reused)
    float f2acc[3];
    #pragma unroll
    for (int j = 0; j < 3; j++) f2acc[j] = f2b[c0 + j];
    #pragma unroll 4
    for (int k = 0; k < 96; k++) {
        float a = m1v[tok * 97 + k];
        const float* wr = w2 + k * 48 + c0;
        #pragma unroll
        for (int j = 0; j < 3; j++) f2acc[j] += a * wr[j];
    }
    __syncthreads();
    #pragma unroll
    for (int j = 0; j < 3; j++)
        arf[tok * 49 + c0 + j] = f2acc[j] + lnr[tok * 49 + c0 + j];
    __syncthreads();

    // cooperative coalesced transposed accumulate into h (NCHW)
    for (int i = tid; i < 768; i += 256) {
        int c = i >> 4, t = i & 15;
        hbuf[(((size_t)(b * 48 + c)) << 12) + pos0 + t] += arf[t * 49 + c];
    }
}

// ---- MFMA flash attention: 64 q/wave (4 fragments sharing K/V loads), split-K x4.
//      64-key chunk double-buffer: prefetch buffers cost 48 VGPR (vs 192 for the
//      old 128-key chunks) -> kernel fits under 256 VGPR -> the grid's 2 blocks/CU
//      co-reside (2 waves/SIMD, ONE pass) instead of >256 forcing 1 wave/SIMD and
//      two serial passes (the unexplained 2x in R7-R11). No launch_bounds cap (a
//      forced cap spills and NaNs - R2/R12). No-max softmax; partials (o, sum p)
//      are plain sums -> additive combine in fused_mlp. Row sum via V ones-row. ----
#define LOADCH2(P, c) { \
    _Pragma("unroll") \
    for (int s_ = 0; s_ < 2; s_++) { \
        const short* kp_ = Kb + ((size_t)((c) * 64 + s_ * 32 + col)) * 32 + g * 8; \
        P##k0[s_] = *(const short8v*)(kp_); \
        P##k1[s_] = *(const short8v*)(kp_ + 512); \
        P##v[s_]  = *(const short8v*)(Vrb + ((c) * 2 + s_) * 512 + vbase); \
    } }

#define STEP4(kc0, kc1, vv) { \
    _Pragma("unroll") \
    for (int f_ = 0; f_ < 4; f_++) { \
        f32x4 z_ = {0.f, 0.f, 0.f, 0.f}; \
        f32x4 s1 = __builtin_amdgcn_mfma_f32_16x16x32_bf16(kc0, qb[f_], z_, 0, 0, 0); \
        f32x4 s2 = __builtin_amdgcn_mfma_f32_16x16x32_bf16(kc1, qb[f_], z_, 0, 0, 0); \
        float p0 = exp2_raw(s1[0]), p1 = exp2_raw(s1[1]); \
        float p2 = exp2_raw(s1[2]), p3 = exp2_raw(s1[3]); \
        float p4 = exp2_raw(s2[0]), p5 = exp2_raw(s2[1]); \
        float p6 = exp2_raw(s2[2]), p7 = exp2_raw(s2[3]); \
        union { short8v sv; unsigned u[4]; } pu_; \
        asm("v_cvt_pk_bf16_f32 %0, %1, %2" : "=v"(pu_.u[0]) : "v"(p0), "v"(p1)); \
        asm("v_cvt_pk_bf16_f32 %0, %1, %2" : "=v"(pu_.u[1]) : "v"(p2), "v"(p3)); \
        asm("v_cvt_pk_bf16_f32 %0, %1, %2" : "=v"(pu_.u[2]) : "v"(p4), "v"(p5)); \
        asm("v_cvt_pk_bf16_f32 %0, %1, %2" : "=v"(pu_.u[3]) : "v"(p6), "v"(p7)); \
        o[f_] = __builtin_amdgcn_mfma_f32_16x16x32_bf16(vv, pu_.sv, o[f_], 0, 0, 0); \
    } }

#define COMPUTECH2(P) { \
    STEP4(P##k0[0], P##k1[0], P##v[0]); \
    STEP4(P##k0[1], P##k1[1], P##v[1]); }

__global__ __launch_bounds__(256) void attn_mfma_kernel(const short* __restrict__ Qbf,
                                                        const short* __restrict__ Kbf,
                                                        const short* __restrict__ Vr,
                                                        float* __restrict__ opart,
                                                        float* __restrict__ ssump) {
    int bid = blockIdx.x;                 // split(4) | qblk(16) | bh(8) = 512 blocks
    int bh = bid & 7;
    int qblk = (bid >> 3) & 15;
    int split = bid >> 7;
    int h = bh & 3, b = bh >> 2;
    int tid = threadIdx.x;
    int wave = tid >> 6;
    int lane = tid & 63;
    int q0 = qblk * 256 + wave * 64;      // 64 q per wave (4 x 16-q fragments)
    int col = lane & 15;
    int g = lane >> 4;

    const short* Kb  = Kbf + (size_t)bh * LL * 32 + (size_t)split * 1024 * 32;
    const short* Vrb = Vr + (size_t)bh * 65536 + (size_t)split * 32 * 512;
    int vbase = col * 32 + g * 8;

    short8v qb[4];
    f32x4 o[4];
    #pragma unroll
    for (int f = 0; f < 4; f++) {
        qb[f] = *(const short8v*)(Qbf + ((size_t)bh * LL + q0 + 16 * f + col) * 32 + g * 8);
        o[f] = (f32x4){0.f, 0.f, 0.f, 0.f};
    }

    short8v a_k0[2], a_k1[2], a_v[2];
    short8v b_k0[2], b_k1[2], b_v[2];

    LOADCH2(a_, 0);
    for (int c = 0; c < 16; c += 2) {
        LOADCH2(b_, c + 1);
        COMPUTECH2(a_);
        if (c + 2 < 16) LOADCH2(a_, c + 2);
        COMPUTECH2(b_);
    }

    // row 12 of o (lane group g==3, j==0) holds this split's sum(p) via V's ones-row
    #pragma unroll
    for (int f = 0; f < 4; f++) {
        float ss = __shfl(o[f][0], 48 + col, 64);
        float* op = opart + (size_t)split * OPART_STRIDE
                  + ((size_t)b * 4096 + q0 + 16 * f + col) * 48 + h * HD;
        #pragma unroll
        for (int j = 0; j < 4; j++) {
            int d = 4 * g + j;
            if (d < HD)
                op[d] = o[f][j];
        }
        if (lane < 16)
            ssump[((size_t)split * 8 + bh) * 4096 + q0 + 16 * f + col] = ss;
    }
}

// ---- last conv as bf16 MFMA GEMM over channel-last U: M=131072 px, N=16 (3 real oc),
//      K=448 (tap*48+ci). Per-wave 16-px tile, 14 MFMAs, no LDS, no syncs. Boundary
//      taps resolved by zero-block pointer select (same idiom as conv_up's gg<54). ----
__global__ __launch_bounds__(256) void lastconv_mfma_kernel(const short* __restrict__ U,
                                                            const short* __restrict__ Wp2,
                                                            const short* __restrict__ zb,
                                                            const float* __restrict__ bias,
                                                            float* __restrict__ out) {
    int tid = threadIdx.x;
    int wave = tid >> 6, lane = tid & 63;
    int t = blockIdx.x * 4 + wave;        // 8192 tiles: b(2) | y(256) | xt(16)
    int xt = t & 15;
    int yy = (t >> 4) & 255;
    int b = t >> 12;
    int col = lane & 15, g = lane >> 4;
    int x = xt * 16 + col;                // A-row pixel x

    const short* Ub = U + (size_t)b * 65536 * 48;
    const short* Bp = Wp2 + col * 32 + g * 8;

    f32x4 acc = {0.f, 0.f, 0.f, 0.f};
    #pragma unroll
    for (int s = 0; s < 14; s++) {
        int gg = 4 * s + g;
        int tap = (gg * 171) >> 10;       // gg/6 for gg<60
        int cig = gg - tap * 6;
        int dy3 = (tap * 11) >> 5;        // tap/3 for tap<9(+)
        int dy = dy3 - 1;
        int dx = tap - dy3 * 3 - 1;
        int yq = yy + dy, xq = x + dx;
        bool ok = (gg < 54) && (yq >= 0) && (yq < 256) && (xq >= 0) && (xq < 256);
        const short* ap = Ub + (ptrdiff_t)(yq * 256 + xq) * 48 + cig * 8;
        ap = ok ? ap : zb;
        short8v av = *(const short8v*)ap;
        short8v bv = *(const short8v*)(Bp + s * 512);
        acc = __builtin_amdgcn_mfma_f32_16x16x32_bf16(av, bv, acc, 0, 0, 0);
    }

    if (col < 3) {
        float bval = bias[col];
        float* op = out + ((size_t)(b * 3 + col) * 256 + yy) * 256 + xt * 16 + 4 * g;
        #pragma unroll
        for (int j = 0; j < 4; j++)
            op[j] = acc[j] + bval;        // C row r=4g+j = pixel-x offset (m89 mapping)
    }
}

static inline int gs(int n) { return (n + 255) / 256; }

extern "C" void kernel_launch(void* const* d_in, const int* in_sizes, int n_in,
                              void* d_out, int out_size, void* d_ws, size_t ws_size,
                              hipStream_t stream) {
    const float* x    = (const float*)d_in[0];
    const float* cf_w = (const float*)d_in[1];
    const float* cf_b = (const float*)d_in[2];
    const float* n1g  = (const float*)d_in[3];
    const float* n1b  = (const float*)d_in[4];
    const float* qkvw = (const float*)d_in[5];
    const float* qkvb = (const float*)d_in[6];
    const float* pw   = (const float*)d_in[7];
    const float* pb   = (const float*)d_in[8];
    const float* n2g  = (const float*)d_in[9];
    const float* n2b  = (const float*)d_in[10];
    const float* f1w  = (const float*)d_in[11];
    const float* f1b  = (const float*)d_in[12];
    const float* f2w  = (const float*)d_in[13];
    const float* f2b  = (const float*)d_in[14];
    const float* upw  = (const float*)d_in[15];
    const float* upb  = (const float*)d_in[16];
    const float* lw   = (const float*)d_in[17];
    const float* lb   = (const float*)d_in[18];

    float* ws = (float*)d_ws;
    const int S_h = BB * D * LL;            // 393216
    float* A_h   = ws;
    float* pool  = ws + S_h;
    float* A_ln1 = pool;

    // U channel-last bf16: [b][256][256][48] shorts = 6291456 shorts = 3145728 floats at pool[0]
    // (written after the block loop; aliases A_ln1 + o_part, both dead by then)
    short* U_bf = (short*)pool;
    // attention split partials: o_part [4][B*L*48]
    float* o_part = pool + 1572864;                    // ends 3145728
    short* Qbf  = (short*)(pool + 3538944);
    short* Kbf  = Qbf + BB * NHEADS * LL * 32;         // +1048576 shorts
    short* Vr   = Kbf + BB * NHEADS * LL * 32;         // ends pool+4849664 floats
    // packs live in the dead gap after Vr (written post-loop)
    short* hbfp = (short*)(pool + 4849664);            // 418240 shorts -> ends 5058784
    short* Wp   = (short*)(pool + 5058784);            // 344064 shorts -> ends 5230816
    short* Wp2  = (short*)(pool + 5230816);            // 7168 shorts   -> ends 5234400
    // ssum partials [4][8][4096]
    float* ssum_part = pool + 5898240;                 // 131072 floats -> ends 6029312

    // conv_first (3 -> 48)
    conv3x3_kernel<<<gs(S_h), 256, 0, stream>>>(x, cf_w, cf_b, A_h, 3, D);

    // zero Q/K/Vr (pads must be 0; Vr ones-row planted; real entries overwritten every block)
    zero16_kernel<<<1536, 256, 0, stream>>>((u64*)Qbf, 393216);
    // pack conv_up + last-conv weights (input-only dependencies)
    pack_w_kernel<<<1344, 256, 0, stream>>>(upw, Wp);
    pack_lw_kernel<<<28, 256, 0, stream>>>(lw, Wp2);

    for (int i = 0; i < NBLK; i++) {
        fused_ln1_qkv_kernel<<<512, 256, 0, stream>>>(
            A_h, n1g + i * D, n1b + i * D,
            qkvw + (size_t)i * D * 3 * D, qkvb + i * 3 * D,
            A_ln1, Qbf, Kbf, Vr);
        attn_mfma_kernel<<<8 * 16 * NSPLIT, 256, 0, stream>>>(Qbf, Kbf, Vr, o_part, ssum_part);
        fused_mlp_kernel<<<512, 256, 0, stream>>>(
            o_part, ssum_part, pw + (size_t)i * D * D, pb + i * D,
            A_ln1, n2g + i * D, n2b + i * D,
            f1w + (size_t)i * D * 2 * D, f1b + i * 2 * D,
            f2w + (size_t)i * 2 * D * D, f2b + i * D,
            A_h);
    }

    // pack h -> bf16 halo'd channel-last, then n-split MFMA conv_up -> bf16 U
    pack_h_kernel<<<1634, 256, 0, stream>>>(A_h, hbfp);
    conv_up_mfma_kernel<<<512, 128, 0, stream>>>(hbfp, Wp, upb, U_bf);

    // last conv: MFMA im2col GEMM over channel-last bf16 U -> f32 out
    lastconv_mfma_kernel<<<2048, 256, 0, stream>>>(
        U_bf, Wp2, hbfp + 2 * 66 * 66 * 48, lb, (float*)d_out);
}

// Round 15
// 272.280 us; speedup vs baseline: 1.0228x; 1.0228x over previous
//
#include <hip/hip_runtime.h>
#include <hip/hip_bf16.h>
#include <math.h>

#define BB 2
#define D 48
#define HH 64
#define WW 64
#define LL 4096      // HH*WW
#define NHEADS 4
#define HD 12
#define NBLK 4
#define CUP 768
#define H2 256
#define W2 256

#define NSPLIT 4
#define OPART_STRIDE 393216   // B*L*48 floats per split

typedef __attribute__((ext_vector_type(8))) short short8v;
typedef __attribute__((ext_vector_type(4))) float f32x4;
typedef unsigned long long u64;

__device__ __forceinline__ short f2bf(float f) {
    __hip_bfloat16 h = __float2bfloat16(f);
    union { __hip_bfloat16 b; short s; } u; u.b = h; return u.s;
}
__device__ __forceinline__ float bf2f(short s) {
    union { float f; unsigned u; } x;
    x.u = ((unsigned)(unsigned short)s) << 16;
    return x.f;
}
// raw 2^x (hardware approx, ~1 ulp; inputs are tiny softmax scores -> safe)
__device__ __forceinline__ float exp2_raw(float x) {
    float r; asm("v_exp_f32 %0, %1" : "=v"(r) : "v"(x)); return r;
}

// ---------------- generic 3x3 SAME conv, f32 (used for conv_first only) ----------------
__global__ void conv3x3_kernel(const float* __restrict__ in, const float* __restrict__ w,
                               const float* __restrict__ bias, float* __restrict__ out,
                               int Cin, int Cout) {
    int idx = blockIdx.x * blockDim.x + threadIdx.x;
    int total = BB * Cout * HH * WW;
    if (idx >= total) return;
    int x = idx % WW;
    int y = (idx / WW) % HH;
    int co = (idx / (WW * HH)) % Cout;
    int b = idx / (WW * HH * Cout);
    float s = bias[co];
    for (int ci = 0; ci < Cin; ci++) {
        const float* ip = in + ((size_t)(b * Cin + ci) * HH) * WW;
        const float* wp = w + (size_t)(co * Cin + ci) * 9;
        #pragma unroll
        for (int ky = 0; ky < 3; ky++) {
            int iy = y + ky - 1;
            if (iy < 0 || iy >= HH) continue;
            #pragma unroll
            for (int kx = 0; kx < 3; kx++) {
                int ix = x + kx - 1;
                if (ix < 0 || ix >= WW) continue;
                s += ip[iy * WW + ix] * wp[ky * 3 + kx];
            }
        }
    }
    out[idx] = s;
}

// ---- pack h (NCHW f32) -> bf16 channel-last with 1-px zero halo: [b][66][66][48] + 64 zero ----
__global__ __launch_bounds__(256) void pack_h_kernel(const float* __restrict__ h,
                                                     short* __restrict__ hbfp) {
    int idx = blockIdx.x * 256 + threadIdx.x;
    const int TOT = 2 * 66 * 66 * 48;    // 418176
    if (idx >= TOT + 64) return;
    if (idx >= TOT) { hbfp[idx] = 0; return; }
    int ci = idx % 48;
    int p = idx / 48;
    int xx = p % 66;
    int q = p / 66;
    int yy = q % 66;
    int b = q / 66;
    short v = 0;
    if (yy >= 1 && yy <= 64 && xx >= 1 && xx <= 64)
        v = f2bf(h[((size_t)(b * 48 + ci) << 12) + (yy - 1) * 64 + (xx - 1)]);
    hbfp[idx] = v;
}

// ---- pack conv_up weights into B-fragment order: Wp[n16][s][col][g][j], K=tap*48+ci pad 448 ----
__global__ __launch_bounds__(256) void pack_w_kernel(const float* __restrict__ w,
                                                     short* __restrict__ Wp) {
    int idx = blockIdx.x * 256 + threadIdx.x;
    if (idx >= 48 * 14 * 512) return;    // 344064
    int j = idx & 7;
    int g = (idx >> 3) & 3;
    int col = (idx >> 5) & 15;
    int s = (idx >> 9) % 14;
    int n16 = idx / (14 * 512);
    int k = 32 * s + 8 * g + j;
    short v = 0;
    if (k < 432) {
        int tap = k / 48, ci = k - tap * 48;
        int co = n16 * 16 + col;
        v = f2bf(w[((size_t)co * 48 + ci) * 9 + tap]);
    }
    Wp[idx] = v;
}

// ---- pack last-conv weights into B-fragment order: Wp2[s][col][g][j], cols 3..15 zero ----
__global__ __launch_bounds__(256) void pack_lw_kernel(const float* __restrict__ w,
                                                      short* __restrict__ Wp2) {
    int idx = blockIdx.x * 256 + threadIdx.x;
    if (idx >= 14 * 512) return;         // 7168
    int j = idx & 7;
    int g = (idx >> 3) & 3;
    int col = (idx >> 5) & 15;
    int s = idx >> 9;
    int k = 32 * s + 8 * g + j;
    short v = 0;
    if (k < 432 && col < 3) {
        int tap = k / 48, ci = k - tap * 48;
        v = f2bf(w[((size_t)col * 48 + ci) * 9 + tap]);
    }
    Wp2[idx] = v;
}

// ---- conv_up as bf16 MFMA GEMM, n-split (R13-proven): block (128 thr) owns one
//      16-px strip; wave w computes n-tiles [24w, 24w+24). Staging: shared LDS,
//      waves write/store DISJOINT 24-channel columns -> no race, NO sync. ----
#define CU_LOADB(P, n) { \
    _Pragma("unroll") \
    for (int s_ = 0; s_ < 14; s_++) \
        P[s_] = *(const short8v*)(Wb + (size_t)(n) * 7168 + s_ * 512); }

#define CU_COMP(P, n) { \
    f32x4 acc = {0.f, 0.f, 0.f, 0.f}; \
    _Pragma("unroll") \
    for (int s_ = 0; s_ < 14; s_++) \
        acc = __builtin_amdgcn_mfma_f32_16x16x32_bf16(av[s_], P[s_], acc, 0, 0, 0); \
    float bval = bias[(n) * 16 + col]; \
    _Pragma("unroll") \
    for (int j = 0; j < 4; j++) \
        Sw[sbase + j * 192 + (n)] = f2bf(acc[j] + bval); }

__global__ __launch_bounds__(128) void conv_up_mfma_kernel(const short* __restrict__ hbfp,
                                                           const short* __restrict__ Wp,
                                                           const float* __restrict__ bias,
                                                           short* __restrict__ U) {
    __shared__ short Sw[12288];          // 24 KB [dyq 4][pos 64][ch 48]; disjoint n cols/wave
    int tid = threadIdx.x;
    int wave = tid >> 6, lane = tid & 63;
    int mt = blockIdx.x;                 // 512 strips: b(2) | y(64) | xt(4)
    int b = mt >> 8;
    int rem = mt & 255;
    int y = rem >> 2;
    int xt = rem & 3;
    int col = lane & 15;
    int g = lane >> 4;
    int x = xt * 16 + col;               // A-row pixel x

    const short* zb = hbfp + 2 * 66 * 66 * 48;   // 64 zero shorts

    // A fragments in registers, loaded once per wave (same im2col addressing)
    short8v av[14];
    #pragma unroll
    for (int s = 0; s < 14; s++) {
        int gg = 4 * s + g;
        int tap = (gg * 171) >> 10;      // gg/6 for gg<60
        int cig = gg - tap * 6;
        int dy = (tap * 11) >> 5;        // tap/3 for tap<9(+)
        int dx = tap - dy * 3;
        const short* ap = hbfp + ((size_t)((b * 66 + y + dy) * 66 + (x + dx)) * 48 + cig * 8);
        ap = (gg < 54) ? ap : zb;
        av[s] = *(const short8v*)ap;
    }

    const short* Wb = Wp + col * 32 + g * 8;
    int dyq = col >> 2, dxq = col & 3;
    int sbase = dyq * 3072 + (16 * g + dxq) * 48;   // + j*192 + n
    int n0 = wave * 24;                  // this wave's n-half

    short8v Ba[14], Bb[14];
    CU_LOADB(Ba, n0);
    for (int n = n0; n < n0 + 24; n += 2) {
        CU_LOADB(Bb, n + 1);
        CU_COMP(Ba, n);
        if (n + 2 < n0 + 24) CU_LOADB(Ba, n + 2);
        CU_COMP(Bb, n + 1);
    }

    // wave-private store of its 24-channel half: 4 rows x 64 positions, 48-B runs
    short* Ub = U + (((size_t)(b * 256 + 4 * y) * 256) + xt * 64) * 48 + n0;
    for (int i = lane; i < 256; i += 64) {
        int row = i >> 6;                // 0..3
        int xx2 = i & 63;
        const short* src = Sw + row * 3072 + xx2 * 48 + n0;
        short* dst = Ub + ((size_t)row * 256 + xx2) * 48;
        *(short8v*)(dst)      = *(const short8v*)(src);
        *(short8v*)(dst + 8)  = *(const short8v*)(src + 8);
        *(short8v*)(dst + 16) = *(const short8v*)(src + 16);
    }
}

// ---- zero bf16 pad regions; plant bf16 1.0 in Vr's padded row dd==12 (sum-row trick) ----
__global__ void zero16_kernel(u64* __restrict__ p, int n) {
    int i = blockIdx.x * 256 + threadIdx.x;
    if (i >= n) return;
    u64 fill = 0ull;
    // short offset of this 8-short chunk, relative to Vr start (Q:1M + K:1M shorts before it)
    int rel = 8 * i - 2097152;
    if (rel >= 0 && rel < 524288 && (((rel >> 5) & 15) == 12))
        fill = 0x3F803F803F803F80ull;     // bf16 1.0 x4
    p[2 * i] = fill;
    p[2 * i + 1] = fill;
}

// ---- fused: LN1 (NCHW) -> ln1 rows + qkv matmul -> bf16 Q/K/Vr (16-tok tiles) ----
__global__ __launch_bounds__(256) void fused_ln1_qkv_kernel(
    const float* __restrict__ hsrc, const float* __restrict__ g1, const float* __restrict__ b1,
    const float* __restrict__ w, const float* __restrict__ bias,
    float* __restrict__ ln1, short* __restrict__ Qbf, short* __restrict__ Kbf,
    short* __restrict__ Vr) {
    __shared__ float hs[48 * 17];
    __shared__ float lnr[16 * 49];
    __shared__ float wl[48 * 144];
    int blk = blockIdx.x;
    int b = blk >> 8;
    int pos0 = (blk & 255) * 16;
    int tid = threadIdx.x;

    for (int i = tid; i < 48 * 144; i += 256) wl[i] = w[i];
    for (int i = tid; i < 48 * 16; i += 256) {
        int ch = i >> 4, p = i & 15;
        hs[ch * 17 + p] = hsrc[((size_t)b * 48 + ch) * 4096 + pos0 + p];
    }
    __syncthreads();

    int tok = tid >> 4, oct = tid & 15;
    int pos = pos0 + tok;
    float v[3];
    float s = 0.f, s2 = 0.f;
    #pragma unroll
    for (int j = 0; j < 3; j++) {
        float x = hs[(oct * 3 + j) * 17 + tok];
        v[j] = x; s += x; s2 += x * x;
    }
    #pragma unroll
    for (int msk = 1; msk < 16; msk <<= 1) {
        s += __shfl_xor(s, msk, 64);
        s2 += __shfl_xor(s2, msk, 64);
    }
    float mu = s * (1.f / 48.f);
    float var = s2 * (1.f / 48.f) - mu * mu;
    float rs = rsqrtf(var + 1e-5f);
    float* go = ln1 + ((size_t)b * 4096 + pos) * 48 + oct * 3;
    #pragma unroll
    for (int j = 0; j < 3; j++) {
        int c = oct * 3 + j;
        float y = (v[j] - mu) * rs * g1[c] + b1[c];
        lnr[tok * 49 + c] = y;
        go[j] = y;
    }
    __syncthreads();

    int c0 = oct * 9;
    float acc[9];
    #pragma unroll
    for (int j = 0; j < 9; j++) acc[j] = bias[c0 + j];
    #pragma unroll 4
    for (int k = 0; k < 48; k++) {
        float a = lnr[tok * 49 + k];
        const float* wr = wl + k * 144 + c0;
        #pragma unroll
        for (int j = 0; j < 9; j++) acc[j] += a * wr[j];
    }

    // 1/sqrt(12) * log2(e): softmax exp becomes a single raw v_exp_f32 (2^x)
    const float scale = 0.41647023f;
    int sstep = pos >> 5, r = pos & 31;
    int g2 = (r < 16) ? (r >> 2) : ((r - 16) >> 2);
    int j2 = (r < 16) ? (r & 3) : 4 + ((r - 16) & 3);
    #pragma unroll
    for (int j = 0; j < 9; j++) {
        int c = c0 + j;
        int which = (c >= 96) ? 2 : (c >= 48 ? 1 : 0);
        int rem = c - which * 48;
        int hh = rem / 12;
        int dd = rem - hh * 12;
        int bh = b * 4 + hh;
        if (which == 0)
            Qbf[((size_t)bh * 4096 + pos) * 32 + dd] = f2bf(acc[j] * scale);
        else if (which == 1)
            Kbf[((size_t)bh * 4096 + pos) * 32 + dd] = f2bf(acc[j]);
        else
            Vr[((size_t)bh * 128 + sstep) * 512 + dd * 32 + g2 * 8 + j2] = f2bf(acc[j]);
    }
}

// ---- fused: split-combine + proj + resid + LN2 + fc1 + GELU + fc2 + resid + h-accum ----
__global__ __launch_bounds__(256) void fused_mlp_kernel(
    const float* __restrict__ opart, const float* __restrict__ ssump,
    const float* __restrict__ pwg, const float* __restrict__ pb,
    const float* __restrict__ ln1, const float* __restrict__ g2v, const float* __restrict__ b2v,
    const float* __restrict__ f1w, const float* __restrict__ f1b,
    const float* __restrict__ f2w, const float* __restrict__ f2b,
    float* __restrict__ hbuf) {
    __shared__ float sm[14640];
    float* wp  = sm;            // 2304  (48x48 proj)
    float* w1  = sm + 2304;     // 4608  (48x96 fc1)
    float* w2  = sm + 6912;     // 4608  (96x48 fc2)
    float* arf = sm + 11520;    // 784   (16x49) attn rows, reused as fc2-out
    float* lnr = sm + 12304;    // 784   (16x49) ln2 rows
    float* m1v = sm + 13088;    // 1552  (16x97) gelu(fc1)

    int blk = blockIdx.x;
    int b = blk >> 8;
    int pos0 = (blk & 255) * 16;
    int tid = threadIdx.x;

    for (int i = tid; i < 2304; i += 256) wp[i] = pwg[i];
    for (int i = tid; i < 4608; i += 256) w1[i] = f1w[i];
    for (int i = tid; i < 4608; i += 256) w2[i] = f2w[i];
    // combine split partials -> normalized attention rows (per-thread, no extra sync deps)
    for (int i = tid; i < 768; i += 256) {
        int t = i / 48, c = i - (i / 48) * 48;
        int hh = c / 12;
        size_t base = ((size_t)b * 4096 + pos0) * 48 + i;
        float stot = 0.f, s = 0.f;
        #pragma unroll
        for (int sp = 0; sp < NSPLIT; sp++) {
            stot += ssump[((size_t)sp * 8 + b * 4 + hh) * 4096 + pos0 + t];
            s += opart[base + (size_t)sp * OPART_STRIDE];
        }
        arf[t * 49 + c] = s / stot;
    }
    __syncthreads();

    int tok = tid >> 4, oct = tid & 15;
    size_t gtok = (size_t)b * 4096 + pos0 + tok;
    int c0 = oct * 3;
    float acc[3];
    #pragma unroll
    for (int j = 0; j < 3; j++) acc[j] = pb[c0 + j];
    #pragma unroll 4
    for (int k = 0; k < 48; k++) {
        float a = arf[tok * 49 + k];
        const float* wr = wp + k * 48 + c0;
        #pragma unroll
        for (int j = 0; j < 3; j++) acc[j] += a * wr[j];
    }
    const float* rp = ln1 + gtok * 48 + c0;
    float x[3]; float s = 0.f, s2 = 0.f;
    #pragma unroll
    for (int j = 0; j < 3; j++) {
        float t = acc[j] + rp[j];
        x[j] = t; s += t; s2 += t * t;
    }
    #pragma unroll
    for (int msk = 1; msk < 16; msk <<= 1) {
        s += __shfl_xor(s, msk, 64);
        s2 += __shfl_xor(s2, msk, 64);
    }
    float mu = s * (1.f / 48.f), var = s2 * (1.f / 48.f) - mu * mu;
    float rs = rsqrtf(var + 1e-5f);
    #pragma unroll
    for (int j = 0; j < 3; j++) {
        int c = c0 + j;
        lnr[tok * 49 + c] = (x[j] - mu) * rs * g2v[c] + b2v[c];
    }
    __syncthreads();

    // fc1 + GELU -> m1v (LDS only)
    int d0 = oct * 6;
    float a2[6];
    #pragma unroll
    for (int j = 0; j < 6; j++) a2[j] = f1b[d0 + j];
    #pragma unroll 4
    for (int k = 0; k < 48; k++) {
        float a = lnr[tok * 49 + k];
        const float* wr = w1 + k * 96 + d0;
        #pragma unroll
        for (int j = 0; j < 6; j++) a2[j] += a * wr[j];
    }
    #pragma unroll
    for (int j = 0; j < 6; j++) {
        float g = a2[j];
        m1v[tok * 97 + d0 + j] = 0.5f * g * (1.f + erff(g * 0.70710678118654752f));
    }
    __syncthreads();

    // fc2 + ln2-residual -> arf (reused)
    float f2acc[3];
    #pragma unroll
    for (int j = 0; j < 3; j++) f2acc[j] = f2b[c0 + j];
    #pragma unroll 4
    for (int k = 0; k < 96; k++) {
        float a = m1v[tok * 97 + k];
        const float* wr = w2 + k * 48 + c0;
        #pragma unroll
        for (int j = 0; j < 3; j++) f2acc[j] += a * wr[j];
    }
    __syncthreads();
    #pragma unroll
    for (int j = 0; j < 3; j++)
        arf[tok * 49 + c0 + j] = f2acc[j] + lnr[tok * 49 + c0 + j];
    __syncthreads();

    // cooperative coalesced transposed accumulate into h (NCHW)
    for (int i = tid; i < 768; i += 256) {
        int c = i >> 4, t = i & 15;
        hbuf[(((size_t)(b * 48 + c)) << 12) + pos0 + t] += arf[t * 49 + c];
    }
}

// ---- MFMA flash attention: 64 q/wave (4 fragments sharing K/V loads), split-K x4,
//      128-key chunk double-buffer (R7-proven pipeline, byte-identical). NOTE: do
//      NOT add a min-waves launch_bounds arg here — the VGPR cap breaks this kernel
//      (NaN, observed R2 and R12). No-max softmax; partials (o, sum p) are plain
//      sums -> additive combine in fused_mlp. Row sum via V ones-row (dd==12). ----
#define LOADCH(P, c) { \
    _Pragma("unroll") \
    for (int s_ = 0; s_ < 4; s_++) { \
        const short* kp_ = Kb + ((size_t)((c) * 128 + s_ * 32 + col)) * 32 + g * 8; \
        P##k0[s_] = *(const short8v*)(kp_); \
        P##k1[s_] = *(const short8v*)(kp_ + 512); \
        P##v[s_]  = *(const short8v*)(Vrb + ((c) * 4 + s_) * 512 + vbase); \
    } }

#define STEP4(kc0, kc1, vv) { \
    _Pragma("unroll") \
    for (int f_ = 0; f_ < 4; f_++) { \
        f32x4 z_ = {0.f, 0.f, 0.f, 0.f}; \
        f32x4 s1 = __builtin_amdgcn_mfma_f32_16x16x32_bf16(kc0, qb[f_], z_, 0, 0, 0); \
        f32x4 s2 = __builtin_amdgcn_mfma_f32_16x16x32_bf16(kc1, qb[f_], z_, 0, 0, 0); \
        float p0 = exp2_raw(s1[0]), p1 = exp2_raw(s1[1]); \
        float p2 = exp2_raw(s1[2]), p3 = exp2_raw(s1[3]); \
        float p4 = exp2_raw(s2[0]), p5 = exp2_raw(s2[1]); \
        float p6 = exp2_raw(s2[2]), p7 = exp2_raw(s2[3]); \
        union { short8v sv; unsigned u[4]; } pu_; \
        asm("v_cvt_pk_bf16_f32 %0, %1, %2" : "=v"(pu_.u[0]) : "v"(p0), "v"(p1)); \
        asm("v_cvt_pk_bf16_f32 %0, %1, %2" : "=v"(pu_.u[1]) : "v"(p2), "v"(p3)); \
        asm("v_cvt_pk_bf16_f32 %0, %1, %2" : "=v"(pu_.u[2]) : "v"(p4), "v"(p5)); \
        asm("v_cvt_pk_bf16_f32 %0, %1, %2" : "=v"(pu_.u[3]) : "v"(p6), "v"(p7)); \
        o[f_] = __builtin_amdgcn_mfma_f32_16x16x32_bf16(vv, pu_.sv, o[f_], 0, 0, 0); \
    } }

#define COMPUTECH4(P) { \
    STEP4(P##k0[0], P##k1[0], P##v[0]); \
    STEP4(P##k0[1], P##k1[1], P##v[1]); \
    STEP4(P##k0[2], P##k1[2], P##v[2]); \
    STEP4(P##k0[3], P##k1[3], P##v[3]); }

__global__ __launch_bounds__(256) void attn_mfma_kernel(const short* __restrict__ Qbf,
                                                        const short* __restrict__ Kbf,
                                                        const short* __restrict__ Vr,
                                                        float* __restrict__ opart,
                                                        float* __restrict__ ssump) {
    int bid = blockIdx.x;                 // split(4) | qblk(16) | bh(8) = 512 blocks
    int bh = bid & 7;
    int qblk = (bid >> 3) & 15;
    int split = bid >> 7;
    int h = bh & 3, b = bh >> 2;
    int tid = threadIdx.x;
    int wave = tid >> 6;
    int lane = tid & 63;
    int q0 = qblk * 256 + wave * 64;      // 64 q per wave (4 x 16-q fragments)
    int col = lane & 15;
    int g = lane >> 4;

    const short* Kb  = Kbf + (size_t)bh * LL * 32 + (size_t)split * 1024 * 32;
    const short* Vrb = Vr + (size_t)bh * 65536 + (size_t)split * 32 * 512;
    int vbase = col * 32 + g * 8;

    short8v qb[4];
    f32x4 o[4];
    #pragma unroll
    for (int f = 0; f < 4; f++) {
        qb[f] = *(const short8v*)(Qbf + ((size_t)bh * LL + q0 + 16 * f + col) * 32 + g * 8);
        o[f] = (f32x4){0.f, 0.f, 0.f, 0.f};
    }

    short8v a_k0[4], a_k1[4], a_v[4];
    short8v b_k0[4], b_k1[4], b_v[4];

    LOADCH(a_, 0);
    for (int c = 0; c < 8; c += 2) {
        LOADCH(b_, c + 1);
        COMPUTECH4(a_);
        if (c + 2 < 8) LOADCH(a_, c + 2);
        COMPUTECH4(b_);
    }

    // row 12 of o (lane group g==3, j==0) holds this split's sum(p) via V's ones-row
    #pragma unroll
    for (int f = 0; f < 4; f++) {
        float ss = __shfl(o[f][0], 48 + col, 64);
        float* op = opart + (size_t)split * OPART_STRIDE
                  + ((size_t)b * 4096 + q0 + 16 * f + col) * 48 + h * HD;
        #pragma unroll
        for (int j = 0; j < 4; j++) {
            int d = 4 * g + j;
            if (d < HD)
                op[d] = o[f][j];
        }
        if (lane < 16)
            ssump[((size_t)split * 8 + bh) * 4096 + q0 + 16 * f + col] = ss;
    }
}

// ---- last conv as bf16 MFMA GEMM over channel-last U: M=131072 px, N=16 (3 real oc),
//      K=448 (tap*48+ci). Per-wave 16-px tile, 14 MFMAs, no LDS, no syncs. Boundary
//      taps resolved by zero-block pointer select (same idiom as conv_up's gg<54). ----
__global__ __launch_bounds__(256) void lastconv_mfma_kernel(const short* __restrict__ U,
                                                            const short* __restrict__ Wp2,
                                                            const short* __restrict__ zb,
                                                            const float* __restrict__ bias,
                                                            float* __restrict__ out) {
    int tid = threadIdx.x;
    int wave = tid >> 6, lane = tid & 63;
    int t = blockIdx.x * 4 + wave;        // 8192 tiles: b(2) | y(256) | xt(16)
    int xt = t & 15;
    int yy = (t >> 4) & 255;
    int b = t >> 12;
    int col = lane & 15, g = lane >> 4;
    int x = xt * 16 + col;                // A-row pixel x

    const short* Ub = U + (size_t)b * 65536 * 48;
    const short* Bp = Wp2 + col * 32 + g * 8;

    f32x4 acc = {0.f, 0.f, 0.f, 0.f};
    #pragma unroll
    for (int s = 0; s < 14; s++) {
        int gg = 4 * s + g;
        int tap = (gg * 171) >> 10;       // gg/6 for gg<60
        int cig = gg - tap * 6;
        int dy3 = (tap * 11) >> 5;        // tap/3 for tap<9(+)
        int dy = dy3 - 1;
        int dx = tap - dy3 * 3 - 1;
        int yq = yy + dy, xq = x + dx;
        bool ok = (gg < 54) && (yq >= 0) && (yq < 256) && (xq >= 0) && (xq < 256);
        const short* ap = Ub + (ptrdiff_t)(yq * 256 + xq) * 48 + cig * 8;
        ap = ok ? ap : zb;
        short8v av = *(const short8v*)ap;
        short8v bv = *(const short8v*)(Bp + s * 512);
        acc = __builtin_amdgcn_mfma_f32_16x16x32_bf16(av, bv, acc, 0, 0, 0);
    }

    if (col < 3) {
        float bval = bias[col];
        float* op = out + ((size_t)(b * 3 + col) * 256 + yy) * 256 + xt * 16 + 4 * g;
        #pragma unroll
        for (int j = 0; j < 4; j++)
            op[j] = acc[j] + bval;        // C row r=4g+j = pixel-x offset (m89 mapping)
    }
}

static inline int gs(int n) { return (n + 255) / 256; }

extern "C" void kernel_launch(void* const* d_in, const int* in_sizes, int n_in,
                              void* d_out, int out_size, void* d_ws, size_t ws_size,
                              hipStream_t stream) {
    const float* x    = (const float*)d_in[0];
    const float* cf_w = (const float*)d_in[1];
    const float* cf_b = (const float*)d_in[2];
    const float* n1g  = (const float*)d_in[3];
    const float* n1b  = (const float*)d_in[4];
    const float* qkvw = (const float*)d_in[5];
    const float* qkvb = (const float*)d_in[6];
    const float* pw   = (const float*)d_in[7];
    const float* pb   = (const float*)d_in[8];
    const float* n2g  = (const float*)d_in[9];
    const float* n2b  = (const float*)d_in[10];
    const float* f1w  = (const float*)d_in[11];
    const float* f1b  = (const float*)d_in[12];
    const float* f2w  = (const float*)d_in[13];
    const float* f2b  = (const float*)d_in[14];
    const float* upw  = (const float*)d_in[15];
    const float* upb  = (const float*)d_in[16];
    const float* lw   = (const float*)d_in[17];
    const float* lb   = (const float*)d_in[18];

    float* ws = (float*)d_ws;
    const int S_h = BB * D * LL;            // 393216
    float* A_h   = ws;
    float* pool  = ws + S_h;
    float* A_ln1 = pool;

    // U channel-last bf16: [b][256][256][48] shorts = 6291456 shorts = 3145728 floats at pool[0]
    // (written after the block loop; aliases A_ln1 + o_part, both dead by then)
    short* U_bf = (short*)pool;
    // attention split partials: o_part [4][B*L*48]
    float* o_part = pool + 1572864;                    // ends 3145728
    short* Qbf  = (short*)(pool + 3538944);
    short* Kbf  = Qbf + BB * NHEADS * LL * 32;         // +1048576 shorts
    short* Vr   = Kbf + BB * NHEADS * LL * 32;         // ends pool+4849664 floats
    // packs live in the dead gap after Vr (written post-loop)
    short* hbfp = (short*)(pool + 4849664);            // 418240 shorts -> ends 5058784
    short* Wp   = (short*)(pool + 5058784);            // 344064 shorts -> ends 5230816
    short* Wp2  = (short*)(pool + 5230816);            // 7168 shorts   -> ends 5234400
    // ssum partials [4][8][4096]
    float* ssum_part = pool + 5898240;                 // 131072 floats -> ends 6029312

    // conv_first (3 -> 48)
    conv3x3_kernel<<<gs(S_h), 256, 0, stream>>>(x, cf_w, cf_b, A_h, 3, D);

    // zero Q/K/Vr (pads must be 0; Vr ones-row planted; real entries overwritten every block)
    zero16_kernel<<<1536, 256, 0, stream>>>((u64*)Qbf, 393216);
    // pack conv_up + last-conv weights (input-only dependencies)
    pack_w_kernel<<<1344, 256, 0, stream>>>(upw, Wp);
    pack_lw_kernel<<<28, 256, 0, stream>>>(lw, Wp2);

    for (int i = 0; i < NBLK; i++) {
        fused_ln1_qkv_kernel<<<512, 256, 0, stream>>>(
            A_h, n1g + i * D, n1b + i * D,
            qkvw + (size_t)i * D * 3 * D, qkvb + i * 3 * D,
            A_ln1, Qbf, Kbf, Vr);
        attn_mfma_kernel<<<8 * 16 * NSPLIT, 256, 0, stream>>>(Qbf, Kbf, Vr, o_part, ssum_part);
        fused_mlp_kernel<<<512, 256, 0, stream>>>(
            o_part, ssum_part, pw + (size_t)i * D * D, pb + i * D,
            A_ln1, n2g + i * D, n2b + i * D,
            f1w + (size_t)i * D * 2 * D, f1b + i * 2 * D,
            f2w + (size_t)i * 2 * D * D, f2b + i * D,
            A_h);
    }

    // pack h -> bf16 halo'd channel-last, then n-split MFMA conv_up -> bf16 U
    pack_h_kernel<<<1634, 256, 0, stream>>>(A_h, hbfp);
    conv_up_mfma_kernel<<<512, 128, 0, stream>>>(hbfp, Wp, upb, U_bf);

    // last conv: MFMA im2col GEMM over channel-last bf16 U -> f32 out
    lastconv_mfma_kernel<<<2048, 256, 0, stream>>>(
        U_bf, Wp2, hbfp + 2 * 66 * 66 * 48, lb, (float*)d_out);
}